// Round 1
// baseline (3037.697 us; speedup 1.0000x reference)
//
#include <hip/hip_runtime.h>

#define N_NODES 32768
#define N_EDGES 1048576
#define PREP_L  467968   // prepped bf16 weights per layer

typedef short bfrag8 __attribute__((ext_vector_type(8)));
typedef float f32x4  __attribute__((ext_vector_type(4)));

#define MFMA(a,b,c) __builtin_amdgcn_mfma_f32_16x16x32_bf16(a,b,c,0,0,0)

__device__ __forceinline__ short f2bf(float f){
    unsigned u = __float_as_uint(f);
    u += 0x7fffu + ((u >> 16) & 1u);
    return (short)(u >> 16);
}
__device__ __forceinline__ float sigm(float x){ return 1.0f/(1.0f + __expf(-x)); }
__device__ __forceinline__ float siluf(float x){ return x * sigm(x); }

// ---------------------------------------------------------------- weight prep
// Per layer layout (bf16 elements):
//  W1t   [64 o][96 k]   k<64: Wss[i][o]/(8*r2); k>=64: Wvv0[k-64][o]*S3/(sqrt32*r2)
//  Wsvt  [32 m][64 i]   Wsv[i][m]/(8*r2)
//  Wvst  [32 n][32 m]   Wvs[m][n]/8
//  Wusst [64 o][5120 k] k<4096: Wuss[i][j][o]/(64 r2); else Wuvv[m][n][o]*S3/(32 r2)
//  Wusvt [1024 nf][64 i] Wusv[i][n][o]/64   (nf = n*32+o)
//  Wuvst [1024 nf][64 j] Wuvs[m][j][o]/64   (nf = m*32+o)
// then Woutt [256 o][64 i] = Wout[i][o]/8
__global__ void k_prep(const float* Wss, const float* Wvv0, const float* Wsv,
                       const float* Wvs, const float* Wuss, const float* Wuvv,
                       const float* Wusv, const float* Wuvs, const float* Wout,
                       short* wp)
{
    int idx = blockIdx.x*256 + threadIdx.x;
    const int total = 2*PREP_L + 16384;
    if (idx >= total) return;
    const float s_ss  = 0.0883883476483f;  // 1/(8*sqrt2)
    const float s_vv  = 0.0721687836487f;  // (1/sqrt3)/8
    const float s_sv  = 0.0883883476483f;
    const float s_vs  = 0.125f;
    const float s_uss = 0.0110485434560f;  // 1/(64*sqrt2)
    const float s_uvv = 0.0127577593310f;  // 1/(32*sqrt6)
    const float s_uvw = 0.015625f;         // 1/64
    float v;
    if (idx >= 2*PREP_L){
        int r = idx - 2*PREP_L; int o = r >> 6, i = r & 63;
        v = Wout[i*256 + o] * 0.125f;
    } else {
        int l = idx / PREP_L; int off = idx - l*PREP_L;
        if (off < 6144){ int o = off/96, k = off - o*96;
            v = (k < 64) ? Wss[l*4096 + k*64 + o]*s_ss
                         : Wvv0[l*2048 + (k-64)*64 + o]*s_vv;
        } else if (off < 8192){ int tt = off - 6144; int m = tt>>6, i = tt&63;
            v = Wsv[l*2048 + i*32 + m]*s_sv;
        } else if (off < 9216){ int tt = off - 8192; int n = tt>>5, m = tt&31;
            v = Wvs[l*1024 + m*32 + n]*s_vs;
        } else if (off < 336896){ int tt = off - 9216; int o = tt/5120, k = tt - o*5120;
            if (k < 4096) v = Wuss[l*262144 + k*64 + o]*s_uss;     // k=i*64+j
            else          v = Wuvv[l*65536 + (k-4096)*64 + o]*s_uvv; // kk=m*32+n
        } else if (off < 402432){ int tt = off - 336896; int nf = tt>>6, i = tt&63;
            int n = nf>>5, o = nf&31;
            v = Wusv[l*65536 + i*1024 + n*32 + o]*s_uvw;
        } else { int tt = off - 402432; int nf = tt>>6, j = tt&63;
            int m = nf>>5, o = nf&31;
            v = Wuvs[l*65536 + m*2048 + j*32 + o]*s_uvw;
        }
    }
    wp[idx] = f2bf(v);
}

// ---------------------------------------------------------------- ns = x@Win/8
__global__ void k_in(const float* __restrict__ x, const float* __restrict__ Win,
                     float* __restrict__ ns)
{
    int wv = threadIdx.x >> 6, o = threadIdx.x & 63;
    int node = blockIdx.x*4 + wv;
    const float* xr = x + (size_t)node*64;
    float acc = 0.f;
    #pragma unroll
    for (int i=0;i<64;i++) acc += xr[i]*Win[i*64+o];
    ns[(size_t)node*64+o] = 0.125f*acc;
}

// ---------------------------------------------------------------- edge phase
// 4 waves/block, each wave: 16 edges/tile, 4 tiles. MFMA for m_s/p/q,
// VALU epilogue: silu, v-gate (mean over 96 via shfl), fp32 atomics scatter.
__global__ __launch_bounds__(256) void k_edge(
        const float* __restrict__ ns, const float* __restrict__ nv,
        const int* __restrict__ eidx, const float* __restrict__ eattr,
        const short* __restrict__ wp_l,
        const float* __restrict__ gmw, const float* __restrict__ gmb,
        float* __restrict__ a_s, float* __restrict__ a_v)
{
    __shared__ __align__(16) short sA1[4][16*104];   // [es*hs | tvv] bf16
    __shared__ __align__(16) short sA2[4][16*72];    // raw hs bf16
    __shared__ __align__(16) short sAv[4][3*16*40];  // es*hv per x
    __shared__ int   sRow[4][16];
    __shared__ float sEv[4][16][4];

    const int t = threadIdx.x;
    const int w = t >> 6, lane = t & 63;
    const int col = lane & 15, quad = lane >> 4;

    const short* W1t  = wp_l;
    const short* Wsvt = wp_l + 6144;
    const short* Wvst = wp_l + 8192;

    bfrag8 b1[3][4], bsv[2][2], bvs[2];
    #pragma unroll
    for (int s=0;s<3;s++)
        #pragma unroll
        for (int nt=0;nt<4;nt++)
            b1[s][nt] = *(const bfrag8*)(W1t + (nt*16+col)*96 + s*32 + quad*8);
    #pragma unroll
    for (int s=0;s<2;s++)
        #pragma unroll
        for (int nt=0;nt<2;nt++)
            bsv[s][nt] = *(const bfrag8*)(Wsvt + (nt*16+col)*64 + s*32 + quad*8);
    #pragma unroll
    for (int nt=0;nt<2;nt++)
        bvs[nt] = *(const bfrag8*)(Wvst + (nt*16+col)*32 + quad*8);

    float gwv[2][3], gbv[2][3];
    #pragma unroll
    for (int h=0;h<2;h++)
        #pragma unroll
        for (int xx=0;xx<3;xx++){
            int k = (h*16+col)*3+xx;
            gwv[h][xx] = gmw[k]; gbv[h][xx] = gmb[k];
        }

    const int waveg = blockIdx.x*4 + w;
    for (int it=0; it<4; it++){
        int tileBase = (waveg + it*16384) * 16;
        { // ---- stage: lane (quad q, edge e) ----
            int e = col, q = quad;
            int eg = tileBase + e;
            int c = eidx[N_EDGES + eg];
            float4 ea = *(const float4*)(eattr + (size_t)eg*4);
            float es = ea.w;
            const float* nsr = ns + (size_t)c*64 + q*16;
            float4 h4[4]; float hq[16];
            #pragma unroll
            for (int a=0;a<4;a++) h4[a] = *(const float4*)(nsr + 4*a);
            #pragma unroll
            for (int a=0;a<4;a++){ hq[4*a]=h4[a].x; hq[4*a+1]=h4[a].y; hq[4*a+2]=h4[a].z; hq[4*a+3]=h4[a].w; }
            const float* nvr = nv + (size_t)c*96 + q*24;
            float4 g4[6]; float hv[24];
            #pragma unroll
            for (int a=0;a<6;a++) g4[a] = *(const float4*)(nvr + 4*a);
            #pragma unroll
            for (int a=0;a<6;a++){ hv[4*a]=g4[a].x; hv[4*a+1]=g4[a].y; hv[4*a+2]=g4[a].z; hv[4*a+3]=g4[a].w; }
            #pragma unroll
            for (int hk=0; hk<2; hk++){
                bfrag8 ve, vr;
                #pragma unroll
                for (int j=0;j<8;j++){ float f = hq[hk*8+j]; ve[j]=f2bf(es*f); vr[j]=f2bf(f); }
                *(bfrag8*)&sA1[w][e*104 + q*16 + hk*8] = ve;
                *(bfrag8*)&sA2[w][e*72  + q*16 + hk*8] = vr;
            }
            bfrag8 vt;
            #pragma unroll
            for (int mi=0;mi<8;mi++)
                vt[mi] = f2bf(hv[mi*3]*ea.x + hv[mi*3+1]*ea.y + hv[mi*3+2]*ea.z);
            *(bfrag8*)&sA1[w][e*104 + 64 + q*8] = vt;
            #pragma unroll
            for (int xx=0;xx<3;xx++){
                bfrag8 vv;
                #pragma unroll
                for (int mi=0;mi<8;mi++) vv[mi] = f2bf(es*hv[mi*3+xx]);
                *(bfrag8*)&sAv[w][xx*640 + e*40 + q*8] = vv;
            }
            if (q==0){
                sRow[w][e] = eidx[eg];
                sEv[w][e][0]=ea.x; sEv[w][e][1]=ea.y; sEv[w][e][2]=ea.z;
            }
        }
        __syncthreads();
        // ---- MFMA ----
        f32x4 accs[4], accp[2], accq[3][2];
        #pragma unroll
        for (int nt=0;nt<4;nt++) accs[nt] = (f32x4){0.f,0.f,0.f,0.f};
        #pragma unroll
        for (int nt=0;nt<2;nt++) accp[nt] = (f32x4){0.f,0.f,0.f,0.f};
        #pragma unroll
        for (int xx=0;xx<3;xx++)
            #pragma unroll
            for (int nt=0;nt<2;nt++) accq[xx][nt] = (f32x4){0.f,0.f,0.f,0.f};
        bfrag8 a1[3], a2[2], av3[3];
        #pragma unroll
        for (int s=0;s<3;s++) a1[s] = *(bfrag8*)&sA1[w][col*104 + s*32 + quad*8];
        #pragma unroll
        for (int s=0;s<2;s++) a2[s] = *(bfrag8*)&sA2[w][col*72 + s*32 + quad*8];
        #pragma unroll
        for (int xx=0;xx<3;xx++) av3[xx] = *(bfrag8*)&sAv[w][xx*640 + col*40 + quad*8];
        #pragma unroll
        for (int s=0;s<3;s++)
            #pragma unroll
            for (int nt=0;nt<4;nt++) accs[nt] = MFMA(a1[s], b1[s][nt], accs[nt]);
        #pragma unroll
        for (int s=0;s<2;s++)
            #pragma unroll
            for (int nt=0;nt<2;nt++) accp[nt] = MFMA(a2[s], bsv[s][nt], accp[nt]);
        #pragma unroll
        for (int xx=0;xx<3;xx++)
            #pragma unroll
            for (int nt=0;nt<2;nt++) accq[xx][nt] = MFMA(av3[xx], bvs[nt], accq[xx][nt]);
        // ---- epilogue: silu, v-gate, atomic scatter ----
        #pragma unroll
        for (int reg=0; reg<4; reg++){
            int e2 = quad*4 + reg;
            int r = sRow[w][e2];
            float evx[3] = {sEv[w][e2][0], sEv[w][e2][1], sEv[w][e2][2]};
            float* asr = a_s + (size_t)r*64;
            #pragma unroll
            for (int nt=0;nt<4;nt++) atomicAdd(asr + nt*16 + col, siluf(accs[nt][reg]));
            float vals[2][3]; float part = 0.f;
            #pragma unroll
            for (int h=0;h<2;h++)
                #pragma unroll
                for (int xx=0;xx<3;xx++){
                    float vvv = accp[h][reg]*evx[xx] + accq[xx][h][reg];
                    vals[h][xx] = vvv; part += vvv;
                }
            part += __shfl_xor(part,1); part += __shfl_xor(part,2);
            part += __shfl_xor(part,4); part += __shfl_xor(part,8);
            float mean = part*(1.0f/96.0f);
            float* avr = a_v + (size_t)r*96;
            #pragma unroll
            for (int h=0;h<2;h++)
                #pragma unroll
                for (int xx=0;xx<3;xx++){
                    float g = sigm(mean*gwv[h][xx] + gbv[h][xx]);
                    atomicAdd(avr + (h*16+col)*3 + xx, vals[h][xx]*g);
                }
        }
        __syncthreads();
    }
}

// ---------------------------------------------------------------- u_s (K=5120 GEMM)
__global__ __launch_bounds__(256) void k_us(
        const float* __restrict__ ns, const float* __restrict__ nvv,
        const float* __restrict__ a_s, const float* __restrict__ a_v,
        const short* __restrict__ Wusst, float* __restrict__ ns_out)
{
    __shared__ __align__(16) float ns16[16*68];
    __shared__ __align__(16) float as16[16*68];
    __shared__ __align__(16) float nv16[16*100];
    __shared__ __align__(16) float av16[16*100];
    __shared__ __align__(16) short sA[16*1032];

    const int t = threadIdx.x;
    const int w = t>>6, lane = t&63, col = lane&15, quad = lane>>4;
    const int nb = blockIdx.x*16;

    for (int idx=t; idx<1024; idx+=256){ int nd = idx>>6, i = idx&63;
        ns16[nd*68+i] = ns[(size_t)(nb+nd)*64+i];
        as16[nd*68+i] = a_s[(size_t)(nb+nd)*64+i];
    }
    for (int idx=t; idx<1536; idx+=256){ int nd = idx/96, i = idx-nd*96;
        nv16[nd*100+i] = nvv[(size_t)(nb+nd)*96+i];
        av16[nd*100+i] = a_v[(size_t)(nb+nd)*96+i];
    }
    __syncthreads();

    f32x4 acc = {0.f,0.f,0.f,0.f};
    for (int c=0;c<5;c++){
        if (c) __syncthreads();
        if (c < 4){ // A[node][k] = ns[i]*a_s[j], k=i*64+j
            #pragma unroll
            for (int itg=0; itg<8; itg++){
                int rid = t + itg*256;
                int nd = rid & 15;
                int kk0 = (rid>>4)<<3;
                int i = (c<<4) + (kk0>>6);
                int j0 = kk0 & 63;
                float nsv = ns16[nd*68 + i];
                const float* ap = &as16[nd*68 + j0];
                float4 x0 = *(const float4*)ap;
                float4 x1 = *(const float4*)(ap+4);
                bfrag8 o8;
                o8[0]=f2bf(nsv*x0.x); o8[1]=f2bf(nsv*x0.y); o8[2]=f2bf(nsv*x0.z); o8[3]=f2bf(nsv*x0.w);
                o8[4]=f2bf(nsv*x1.x); o8[5]=f2bf(nsv*x1.y); o8[6]=f2bf(nsv*x1.z); o8[7]=f2bf(nsv*x1.w);
                *(bfrag8*)&sA[nd*1032 + kk0] = o8;
            }
        } else { // P[m][n] = sum_x nv[m,x]*a_v[n,x]
            #pragma unroll
            for (int itg=0; itg<8; itg++){
                int rid = t + itg*256;
                int nd = rid & 15;
                int kk0 = (rid>>4)<<3;
                int m = kk0>>5, n0 = kk0&31;
                float v0 = nv16[nd*100 + m*3];
                float v1 = nv16[nd*100 + m*3+1];
                float v2 = nv16[nd*100 + m*3+2];
                const float* vp = &av16[nd*100 + n0*3];
                float yf[24];
                #pragma unroll
                for (int a=0;a<6;a++){ float4 y = *(const float4*)(vp+4*a);
                    yf[4*a]=y.x; yf[4*a+1]=y.y; yf[4*a+2]=y.z; yf[4*a+3]=y.w; }
                bfrag8 o8;
                #pragma unroll
                for (int jj=0;jj<8;jj++)
                    o8[jj] = f2bf(v0*yf[jj*3] + v1*yf[jj*3+1] + v2*yf[jj*3+2]);
                *(bfrag8*)&sA[nd*1032 + kk0] = o8;
            }
        }
        __syncthreads();
        const short* bp = Wusst + (size_t)(w*16+col)*5120 + c*1024 + quad*8;
        #pragma unroll
        for (int s=0;s<32;s++){
            bfrag8 a = *(bfrag8*)&sA[col*1032 + s*32 + quad*8];
            bfrag8 b = *(const bfrag8*)(bp + s*32);
            acc = MFMA(a, b, acc);
        }
    }
    #pragma unroll
    for (int reg=0; reg<4; reg++){
        int nd = quad*4 + reg;
        int o = w*16 + col;
        ns_out[(size_t)(nb+nd)*64 + o] = ns16[nd*68 + o] + siluf(acc[reg]);
    }
}

// ---------------------------------------------------------------- u_v (two K=64 GEMMs + fused contraction + gate)
__global__ __launch_bounds__(256) void k_uv(
        const float* __restrict__ ns, const float* __restrict__ nvv,
        const float* __restrict__ a_s, const float* __restrict__ a_v,
        const short* __restrict__ Wusvt, const short* __restrict__ Wuvst,
        const float* __restrict__ guw, const float* __restrict__ gub,
        float* __restrict__ nv_out)
{
    __shared__ __align__(16) short nsbf[16*72];
    __shared__ __align__(16) short asbf[16*72];
    __shared__ __align__(16) float nv16[16*100];
    __shared__ __align__(16) float av16[16*100];
    __shared__ float uvb[2][16][96];

    const int t = threadIdx.x;
    const int w = t>>6, lane = t&63, col = lane&15, quad = lane>>4;
    const int nb = blockIdx.x*16;

    for (int idx=t; idx<1024; idx+=256){ int nd = idx>>6, i = idx&63;
        nsbf[nd*72+i] = f2bf(ns[(size_t)(nb+nd)*64+i]);
        asbf[nd*72+i] = f2bf(a_s[(size_t)(nb+nd)*64+i]);
    }
    for (int idx=t; idx<1536; idx+=256){ int nd = idx/96, i = idx-nd*96;
        nv16[nd*100+i] = nvv[(size_t)(nb+nd)*96+i];
        av16[nd*100+i] = a_v[(size_t)(nb+nd)*96+i];
    }
    __syncthreads();

    const int h = w>>1, o0 = (w&1)*16;
    const short* src = h ? asbf : nsbf;   // h=0: U1 = ns@Wusv (⊗a_v); h=1: U2 = a_s@Wuvs (⊗nv)
    bfrag8 a0 = *(bfrag8*)&src[col*72 + quad*8];
    bfrag8 a1 = *(bfrag8*)&src[col*72 + 32 + quad*8];
    const short* Bt = h ? Wuvst : Wusvt;
    const float* M  = h ? nv16 : av16;
    float uva[3][4] = {};
    for (int n=0;n<32;n++){
        f32x4 acc = {0.f,0.f,0.f,0.f};
        const short* bp = Bt + (size_t)((n<<5) + o0 + col)*64 + quad*8;
        bfrag8 b0 = *(const bfrag8*)(bp);
        bfrag8 b1 = *(const bfrag8*)(bp + 32);
        acc = MFMA(a0,b0,acc);
        acc = MFMA(a1,b1,acc);
        #pragma unroll
        for (int reg=0;reg<4;reg++){
            int nd = quad*4+reg;
            float m0 = M[nd*100 + n*3];
            float m1 = M[nd*100 + n*3+1];
            float m2 = M[nd*100 + n*3+2];
            uva[0][reg] += acc[reg]*m0;
            uva[1][reg] += acc[reg]*m1;
            uva[2][reg] += acc[reg]*m2;
        }
    }
    #pragma unroll
    for (int reg=0;reg<4;reg++){
        int nd = quad*4+reg;
        #pragma unroll
        for (int xx=0;xx<3;xx++)
            uvb[h][nd][(o0+col)*3+xx] = uva[xx][reg];
    }
    __syncthreads();
    {
        int nd = t>>4, j = t&15;
        float part = 0.f;
        #pragma unroll
        for (int kk=j; kk<96; kk+=16) part += uvb[0][nd][kk] + uvb[1][nd][kk];
        part += __shfl_xor(part,1); part += __shfl_xor(part,2);
        part += __shfl_xor(part,4); part += __shfl_xor(part,8);
        float mean = part*(1.0f/96.0f);
        #pragma unroll
        for (int q2=0;q2<6;q2++){
            int kk = j*6 + q2;
            float uv = uvb[0][nd][kk] + uvb[1][nd][kk];
            float g = sigm(mean*guw[kk] + gub[kk]);
            nv_out[(size_t)(nb+nd)*96 + kk] = nv16[nd*100+kk] + uv*g;
        }
    }
}

// ---------------------------------------------------------------- out = ns@Wout/8
__global__ __launch_bounds__(256) void k_out(const float* __restrict__ ns,
                                             const short* __restrict__ Woutt,
                                             float* __restrict__ outp)
{
    __shared__ __align__(16) short nsbf[16*72];
    const int t = threadIdx.x;
    const int w = t>>6, lane = t&63, col = lane&15, quad = lane>>4;
    const int nb = blockIdx.x*16;
    for (int idx=t; idx<1024; idx+=256){ int nd=idx>>6, i=idx&63;
        nsbf[nd*72+i] = f2bf(ns[(size_t)(nb+nd)*64+i]); }
    __syncthreads();
    bfrag8 a0 = *(bfrag8*)&nsbf[col*72 + quad*8];
    bfrag8 a1 = *(bfrag8*)&nsbf[col*72 + 32 + quad*8];
    #pragma unroll
    for (int nt=0;nt<4;nt++){
        int o = w*64 + nt*16 + col;
        const short* bp = Woutt + (size_t)o*64 + quad*8;
        bfrag8 b0 = *(const bfrag8*)bp;
        bfrag8 b1 = *(const bfrag8*)(bp+32);
        f32x4 acc = {0.f,0.f,0.f,0.f};
        acc = MFMA(a0,b0,acc);
        acc = MFMA(a1,b1,acc);
        #pragma unroll
        for (int reg=0;reg<4;reg++)
            outp[(size_t)(nb + quad*4+reg)*256 + o] = acc[reg];
    }
}

// ---------------------------------------------------------------- launch
extern "C" void kernel_launch(void* const* d_in, const int* in_sizes, int n_in,
                              void* d_out, int out_size, void* d_ws, size_t ws_size,
                              hipStream_t stream)
{
    const float* x     = (const float*)d_in[0];
    const float* eattr = (const float*)d_in[1];
    const float* Win   = (const float*)d_in[2];
    const float* Wout  = (const float*)d_in[3];
    const float* Wss   = (const float*)d_in[4];
    const float* Wvv0  = (const float*)d_in[5];
    const float* Wsv   = (const float*)d_in[6];
    const float* Wvs   = (const float*)d_in[7];
    const float* gmw   = (const float*)d_in[8];
    const float* gmb   = (const float*)d_in[9];
    const float* Wuss  = (const float*)d_in[10];
    const float* Wuvv  = (const float*)d_in[11];
    const float* Wusv  = (const float*)d_in[12];
    const float* Wuvs  = (const float*)d_in[13];
    const float* guw   = (const float*)d_in[14];
    const float* gub   = (const float*)d_in[15];
    const int*   eidx  = (const int*)d_in[16];
    float* outp = (float*)d_out;

    char* p = (char*)d_ws;
    float* ns_a = (float*)p; p += (size_t)N_NODES*64*4;
    float* ns_b = (float*)p; p += (size_t)N_NODES*64*4;
    float* nv_a = (float*)p; p += (size_t)N_NODES*96*4;
    float* nv_b = (float*)p; p += (size_t)N_NODES*96*4;
    float* a_s  = (float*)p; p += (size_t)N_NODES*64*4;   // a_s,a_v contiguous (one memset)
    float* a_v  = (float*)p; p += (size_t)N_NODES*96*4;
    short* wp   = (short*)p;

    k_prep<<<3720, 256, 0, stream>>>(Wss,Wvv0,Wsv,Wvs,Wuss,Wuvv,Wusv,Wuvs,Wout,wp);
    hipMemsetAsync(nv_a, 0, (size_t)N_NODES*96*4, stream);
    k_in<<<N_NODES/4, 256, 0, stream>>>(x, Win, ns_a);

    for (int l=0;l<2;l++){
        const float* cns = l ? ns_b : ns_a;
        const float* cnv = l ? nv_b : nv_a;
        float* nns = l ? ns_a : ns_b;
        float* nnv = l ? nv_a : nv_b;
        hipMemsetAsync(a_s, 0, (size_t)N_NODES*(64+96)*4, stream);
        k_edge<<<4096, 256, 0, stream>>>(cns, cnv, eidx, eattr,
                                         wp + (size_t)l*PREP_L,
                                         gmw + l*96, gmb + l*96, a_s, a_v);
        k_uv<<<N_NODES/16, 256, 0, stream>>>(cns, cnv, a_s, a_v,
                                             wp + (size_t)l*PREP_L + 336896,
                                             wp + (size_t)l*PREP_L + 402432,
                                             guw + l*96, gub + l*96, nnv);
        k_us<<<N_NODES/16, 256, 0, stream>>>(cns, cnv, a_s, a_v,
                                             wp + (size_t)l*PREP_L + 9216, nns);
    }
    k_out<<<N_NODES/16, 256, 0, stream>>>(ns_a, wp + (size_t)2*PREP_L, outp);
}

// Round 3
// 1452.997 us; speedup vs baseline: 2.0906x; 2.0906x over previous
//
#include <hip/hip_runtime.h>

#define N_NODES 32768
#define N_EDGES 1048576
#define PREP_L  467968   // prepped bf16 weights per layer

typedef short bfrag8 __attribute__((ext_vector_type(8)));
typedef float f32x4  __attribute__((ext_vector_type(4)));

#define MFMA(a,b,c) __builtin_amdgcn_mfma_f32_16x16x32_bf16(a,b,c,0,0,0)

__device__ __forceinline__ short f2bf(float f){
    unsigned u = __float_as_uint(f);
    u += 0x7fffu + ((u >> 16) & 1u);
    return (short)(u >> 16);
}
__device__ __forceinline__ float sigm(float x){ return 1.0f/(1.0f + __expf(-x)); }
__device__ __forceinline__ float siluf(float x){ return x * sigm(x); }

// ---------------------------------------------------------------- weight prep
__global__ void k_prep(const float* Wss, const float* Wvv0, const float* Wsv,
                       const float* Wvs, const float* Wuss, const float* Wuvv,
                       const float* Wusv, const float* Wuvs, const float* Wout,
                       short* wp)
{
    int idx = blockIdx.x*256 + threadIdx.x;
    const int total = 2*PREP_L + 16384;
    if (idx >= total) return;
    const float s_ss  = 0.0883883476483f;  // 1/(8*sqrt2)
    const float s_vv  = 0.0721687836487f;  // (1/sqrt3)/8
    const float s_sv  = 0.0883883476483f;
    const float s_vs  = 0.125f;
    const float s_uss = 0.0110485434560f;  // 1/(64*sqrt2)
    const float s_uvv = 0.0127577593310f;  // 1/(32*sqrt6)
    const float s_uvw = 0.015625f;         // 1/64
    float v;
    if (idx >= 2*PREP_L){
        int r = idx - 2*PREP_L; int o = r >> 6, i = r & 63;
        v = Wout[i*256 + o] * 0.125f;
    } else {
        int l = idx / PREP_L; int off = idx - l*PREP_L;
        if (off < 6144){ int o = off/96, k = off - o*96;
            v = (k < 64) ? Wss[l*4096 + k*64 + o]*s_ss
                         : Wvv0[l*2048 + (k-64)*64 + o]*s_vv;
        } else if (off < 8192){ int tt = off - 6144; int m = tt>>6, i = tt&63;
            v = Wsv[l*2048 + i*32 + m]*s_sv;
        } else if (off < 9216){ int tt = off - 8192; int n = tt>>5, m = tt&31;
            v = Wvs[l*1024 + m*32 + n]*s_vs;
        } else if (off < 336896){ int tt = off - 9216; int o = tt/5120, k = tt - o*5120;
            if (k < 4096) v = Wuss[l*262144 + k*64 + o]*s_uss;
            else          v = Wuvv[l*65536 + (k-4096)*64 + o]*s_uvv;
        } else if (off < 402432){ int tt = off - 336896; int nf = tt>>6, i = tt&63;
            int n = nf>>5, o = nf&31;
            v = Wusv[l*65536 + i*1024 + n*32 + o]*s_uvw;
        } else { int tt = off - 402432; int nf = tt>>6, j = tt&63;
            int m = nf>>5, o = nf&31;
            v = Wuvs[l*65536 + m*2048 + j*32 + o]*s_uvw;
        }
    }
    wp[idx] = f2bf(v);
}

// ---------------------------------------------------------------- ns = x@Win/8
__global__ void k_in(const float* __restrict__ x, const float* __restrict__ Win,
                     float* __restrict__ ns)
{
    int wv = threadIdx.x >> 6, o = threadIdx.x & 63;
    int node = blockIdx.x*4 + wv;
    const float* xr = x + (size_t)node*64;
    float acc = 0.f;
    #pragma unroll
    for (int i=0;i<64;i++) acc += xr[i]*Win[i*64+o];
    ns[(size_t)node*64+o] = 0.125f*acc;
}

// ---------------------------------------------------------------- sort: histogram
__global__ void k_hist(const int* __restrict__ eidx, int* __restrict__ cnt)
{
    int e = blockIdx.x*256 + threadIdx.x;
    atomicAdd(&cnt[eidx[e]], 1);
}

// ---------------------------------------------------------------- sort: scan (1 block)
__global__ void k_scan(const int* __restrict__ cnt, int* __restrict__ cursor)
{
    __shared__ int part[256];
    int t = threadIdx.x;
    int base = t*128;
    int s = 0;
    for (int i=0;i<128;i++) s += cnt[base+i];
    part[t] = s; __syncthreads();
    for (int off=1; off<256; off<<=1){
        int v = (t>=off) ? part[t-off] : 0;
        __syncthreads();
        part[t] += v;
        __syncthreads();
    }
    int run = part[t] - s;   // exclusive prefix
    for (int i=0;i<128;i++){ cursor[base+i] = run; run += cnt[base+i]; }
}

// ---------------------------------------------------------------- sort: scatter + pre-gather
__global__ void k_scatter(const int* __restrict__ eidx, const float* __restrict__ eattr,
                          int* __restrict__ cursor, int* __restrict__ col_s,
                          int* __restrict__ row_s, float4* __restrict__ ea_s)
{
    int e = blockIdx.x*256 + threadIdx.x;
    int r = eidx[e];
    int d = atomicAdd(&cursor[r], 1);
    row_s[d] = r;
    col_s[d] = eidx[N_EDGES + e];
    ea_s[d]  = ((const float4*)eattr)[e];
}

// ---------------------------------------------------------------- edge phase (sorted slots)
__global__ __launch_bounds__(256) void k_edge(
        const float* __restrict__ ns, const float* __restrict__ nv,
        const int* __restrict__ col_s, const int* __restrict__ row_s,
        const float4* __restrict__ ea_s,
        const short* __restrict__ wp_l,
        const float* __restrict__ gmw, const float* __restrict__ gmb,
        float* __restrict__ a_s, float* __restrict__ a_v)
{
    __shared__ __align__(16) short sA1[4][16*104];   // [es*hs | tvv] bf16
    __shared__ __align__(16) short sA2[4][16*72];    // raw hs bf16
    __shared__ __align__(16) short sAv[4][3*16*40];  // es*hv per x
    __shared__ int   sRow[4][16];
    __shared__ float sEv[4][16][3];
    __shared__ float sAcc[32*160];                   // row-window accumulator

    const int t = threadIdx.x;
    const int w = t >> 6, lane = t & 63;
    const int col = lane & 15, quad = lane >> 4;
    const int blockStart = blockIdx.x*256;
    const int rfirst = row_s[blockStart];

    for (int i=t; i<32*160; i+=256) sAcc[i] = 0.f;

    const short* W1t  = wp_l;
    const short* Wsvt = wp_l + 6144;
    const short* Wvst = wp_l + 8192;

    bfrag8 b1[3][4], bsv[2][2], bvs[2];
    #pragma unroll
    for (int s=0;s<3;s++)
        #pragma unroll
        for (int nt=0;nt<4;nt++)
            b1[s][nt] = *(const bfrag8*)(W1t + (nt*16+col)*96 + s*32 + quad*8);
    #pragma unroll
    for (int s=0;s<2;s++)
        #pragma unroll
        for (int nt=0;nt<2;nt++)
            bsv[s][nt] = *(const bfrag8*)(Wsvt + (nt*16+col)*64 + s*32 + quad*8);
    #pragma unroll
    for (int nt=0;nt<2;nt++)
        bvs[nt] = *(const bfrag8*)(Wvst + (nt*16+col)*32 + quad*8);

    float gwv[2][3], gbv[2][3];
    #pragma unroll
    for (int h=0;h<2;h++)
        #pragma unroll
        for (int xx=0;xx<3;xx++){
            int k = (h*16+col)*3+xx;
            gwv[h][xx] = gmw[k]; gbv[h][xx] = gmb[k];
        }

    auto emit = [&](int r, int f, float v){
        int rl = r - rfirst;
        if (rl < 32) atomicAdd(&sAcc[rl*160 + f], v);
        else if (f < 64) atomicAdd(&a_s[(size_t)r*64 + f], v);
        else             atomicAdd(&a_v[(size_t)r*96 + f - 64], v);
    };

    __syncthreads();

    for (int it=0; it<4; it++){
        int tileBase = blockStart + w*64 + it*16;
        { // ---- stage: lane (quad q, edge e) ----
            int e = col, q = quad;
            int sg = tileBase + e;
            int c = col_s[sg];
            float4 ea = ea_s[sg];
            float es = ea.w;
            const float* nsr = ns + (size_t)c*64 + q*16;
            float4 h4[4]; float hq[16];
            #pragma unroll
            for (int a=0;a<4;a++) h4[a] = *(const float4*)(nsr + 4*a);
            #pragma unroll
            for (int a=0;a<4;a++){ hq[4*a]=h4[a].x; hq[4*a+1]=h4[a].y; hq[4*a+2]=h4[a].z; hq[4*a+3]=h4[a].w; }
            const float* nvr = nv + (size_t)c*96 + q*24;
            float4 g4[6]; float hv[24];
            #pragma unroll
            for (int a=0;a<6;a++) g4[a] = *(const float4*)(nvr + 4*a);
            #pragma unroll
            for (int a=0;a<6;a++){ hv[4*a]=g4[a].x; hv[4*a+1]=g4[a].y; hv[4*a+2]=g4[a].z; hv[4*a+3]=g4[a].w; }
            #pragma unroll
            for (int hk=0; hk<2; hk++){
                bfrag8 ve, vr;
                #pragma unroll
                for (int j=0;j<8;j++){ float f = hq[hk*8+j]; ve[j]=f2bf(es*f); vr[j]=f2bf(f); }
                *(bfrag8*)&sA1[w][e*104 + q*16 + hk*8] = ve;
                *(bfrag8*)&sA2[w][e*72  + q*16 + hk*8] = vr;
            }
            bfrag8 vt;
            #pragma unroll
            for (int mi=0;mi<8;mi++)
                vt[mi] = f2bf(hv[mi*3]*ea.x + hv[mi*3+1]*ea.y + hv[mi*3+2]*ea.z);
            *(bfrag8*)&sA1[w][e*104 + 64 + q*8] = vt;
            #pragma unroll
            for (int xx=0;xx<3;xx++){
                bfrag8 vv;
                #pragma unroll
                for (int mi=0;mi<8;mi++) vv[mi] = f2bf(es*hv[mi*3+xx]);
                *(bfrag8*)&sAv[w][xx*640 + e*40 + q*8] = vv;
            }
            if (q==0){
                sRow[w][e] = row_s[sg];
                sEv[w][e][0]=ea.x; sEv[w][e][1]=ea.y; sEv[w][e][2]=ea.z;
            }
        }
        __syncthreads();
        // ---- MFMA ----
        f32x4 accs[4], accp[2], accq[3][2];
        #pragma unroll
        for (int nt=0;nt<4;nt++) accs[nt] = (f32x4){0.f,0.f,0.f,0.f};
        #pragma unroll
        for (int nt=0;nt<2;nt++) accp[nt] = (f32x4){0.f,0.f,0.f,0.f};
        #pragma unroll
        for (int xx=0;xx<3;xx++)
            #pragma unroll
            for (int nt=0;nt<2;nt++) accq[xx][nt] = (f32x4){0.f,0.f,0.f,0.f};
        bfrag8 a1[3], a2[2], av3[3];
        #pragma unroll
        for (int s=0;s<3;s++) a1[s] = *(bfrag8*)&sA1[w][col*104 + s*32 + quad*8];
        #pragma unroll
        for (int s=0;s<2;s++) a2[s] = *(bfrag8*)&sA2[w][col*72 + s*32 + quad*8];
        #pragma unroll
        for (int xx=0;xx<3;xx++) av3[xx] = *(bfrag8*)&sAv[w][xx*640 + col*40 + quad*8];
        #pragma unroll
        for (int s=0;s<3;s++)
            #pragma unroll
            for (int nt=0;nt<4;nt++) accs[nt] = MFMA(a1[s], b1[s][nt], accs[nt]);
        #pragma unroll
        for (int s=0;s<2;s++)
            #pragma unroll
            for (int nt=0;nt<2;nt++) accp[nt] = MFMA(a2[s], bsv[s][nt], accp[nt]);
        #pragma unroll
        for (int xx=0;xx<3;xx++)
            #pragma unroll
            for (int nt=0;nt<2;nt++) accq[xx][nt] = MFMA(av3[xx], bvs[nt], accq[xx][nt]);

        // ---- epilogue: silu + v-gate per edge, then hierarchical aggregation ----
        float sv[4][4];     // [nt][reg]
        float gv[2][3][4];  // [h][xx][reg]
        #pragma unroll
        for (int reg=0; reg<4; reg++){
            int e2 = quad*4 + reg;
            float evx[3] = {sEv[w][e2][0], sEv[w][e2][1], sEv[w][e2][2]};
            #pragma unroll
            for (int nt=0;nt<4;nt++) sv[nt][reg] = siluf(accs[nt][reg]);
            float vals[2][3]; float part = 0.f;
            #pragma unroll
            for (int h=0;h<2;h++)
                #pragma unroll
                for (int xx=0;xx<3;xx++){
                    float vvv = accp[h][reg]*evx[xx] + accq[xx][h][reg];
                    vals[h][xx] = vvv; part += vvv;
                }
            part += __shfl_xor(part,1); part += __shfl_xor(part,2);
            part += __shfl_xor(part,4); part += __shfl_xor(part,8);
            float mean = part*(1.0f/96.0f);
            #pragma unroll
            for (int h=0;h<2;h++)
                #pragma unroll
                for (int xx=0;xx<3;xx++)
                    gv[h][xx][reg] = vals[h][xx]*sigm(mean*gwv[h][xx] + gbv[h][xx]);
        }
        int r0 = sRow[w][0], r15 = sRow[w][15];
        if (r0 == r15){
            #pragma unroll
            for (int nt=0;nt<4;nt++){
                float s = sv[nt][0]+sv[nt][1]+sv[nt][2]+sv[nt][3];
                s += __shfl_xor(s,16); s += __shfl_xor(s,32);
                if (quad==0) emit(r0, nt*16+col, s);
            }
            #pragma unroll
            for (int h=0;h<2;h++)
                #pragma unroll
                for (int xx=0;xx<3;xx++){
                    float s = gv[h][xx][0]+gv[h][xx][1]+gv[h][xx][2]+gv[h][xx][3];
                    s += __shfl_xor(s,16); s += __shfl_xor(s,32);
                    if (quad==0) emit(r0, 64 + (h*16+col)*3+xx, s);
                }
        } else {
            int rq[4];
            #pragma unroll
            for (int reg=0;reg<4;reg++) rq[reg] = sRow[w][quad*4+reg];
            bool c1 = rq[1]==rq[0], c2 = rq[2]==rq[1], c3 = rq[3]==rq[2];
            auto seg = [&](int f, float v0, float v1, float v2, float v3){
                float run = v0;
                if (c1) run += v1; else { emit(rq[0], f, run); run = v1; }
                if (c2) run += v2; else { emit(rq[1], f, run); run = v2; }
                if (c3) run += v3; else { emit(rq[2], f, run); run = v3; }
                emit(rq[3], f, run);
            };
            #pragma unroll
            for (int nt=0;nt<4;nt++)
                seg(nt*16+col, sv[nt][0], sv[nt][1], sv[nt][2], sv[nt][3]);
            #pragma unroll
            for (int h=0;h<2;h++)
                #pragma unroll
                for (int xx=0;xx<3;xx++)
                    seg(64 + (h*16+col)*3+xx, gv[h][xx][0], gv[h][xx][1], gv[h][xx][2], gv[h][xx][3]);
        }
        __syncthreads();
    }

    // ---- flush window to global (atomics; zeros skipped) ----
    int rlast = row_s[blockStart + 255];
    int nr = rlast - rfirst + 1; if (nr > 32) nr = 32;
    for (int i=t; i<nr*160; i+=256){
        float v = sAcc[i];
        if (v != 0.f){
            int rl = i/160, f = i - rl*160;
            int r = rfirst + rl;
            if (f < 64) atomicAdd(&a_s[(size_t)r*64 + f], v);
            else        atomicAdd(&a_v[(size_t)r*96 + f - 64], v);
        }
    }
}

// ---------------------------------------------------------------- u_s (K=5120 GEMM)
__global__ __launch_bounds__(256) void k_us(
        const float* __restrict__ ns, const float* __restrict__ nvv,
        const float* __restrict__ a_s, const float* __restrict__ a_v,
        const short* __restrict__ Wusst, float* __restrict__ ns_out)
{
    __shared__ __align__(16) float ns16[16*68];
    __shared__ __align__(16) float as16[16*68];
    __shared__ __align__(16) float nv16[16*100];
    __shared__ __align__(16) float av16[16*100];
    __shared__ __align__(16) short sA[16*1032];

    const int t = threadIdx.x;
    const int w = t>>6, lane = t&63, col = lane&15, quad = lane>>4;
    const int nb = blockIdx.x*16;

    for (int idx=t; idx<1024; idx+=256){ int nd = idx>>6, i = idx&63;
        ns16[nd*68+i] = ns[(size_t)(nb+nd)*64+i];
        as16[nd*68+i] = a_s[(size_t)(nb+nd)*64+i];
    }
    for (int idx=t; idx<1536; idx+=256){ int nd = idx/96, i = idx-nd*96;
        nv16[nd*100+i] = nvv[(size_t)(nb+nd)*96+i];
        av16[nd*100+i] = a_v[(size_t)(nb+nd)*96+i];
    }
    __syncthreads();

    f32x4 acc = {0.f,0.f,0.f,0.f};
    for (int c=0;c<5;c++){
        if (c) __syncthreads();
        if (c < 4){
            #pragma unroll
            for (int itg=0; itg<8; itg++){
                int rid = t + itg*256;
                int nd = rid & 15;
                int kk0 = (rid>>4)<<3;
                int i = (c<<4) + (kk0>>6);
                int j0 = kk0 & 63;
                float nsv = ns16[nd*68 + i];
                const float* ap = &as16[nd*68 + j0];
                float4 x0 = *(const float4*)ap;
                float4 x1 = *(const float4*)(ap+4);
                bfrag8 o8;
                o8[0]=f2bf(nsv*x0.x); o8[1]=f2bf(nsv*x0.y); o8[2]=f2bf(nsv*x0.z); o8[3]=f2bf(nsv*x0.w);
                o8[4]=f2bf(nsv*x1.x); o8[5]=f2bf(nsv*x1.y); o8[6]=f2bf(nsv*x1.z); o8[7]=f2bf(nsv*x1.w);
                *(bfrag8*)&sA[nd*1032 + kk0] = o8;
            }
        } else {
            #pragma unroll
            for (int itg=0; itg<8; itg++){
                int rid = t + itg*256;
                int nd = rid & 15;
                int kk0 = (rid>>4)<<3;
                int m = kk0>>5, n0 = kk0&31;
                float v0 = nv16[nd*100 + m*3];
                float v1 = nv16[nd*100 + m*3+1];
                float v2 = nv16[nd*100 + m*3+2];
                const float* vp = &av16[nd*100 + n0*3];
                float yf[24];
                #pragma unroll
                for (int a=0;a<6;a++){ float4 y = *(const float4*)(vp+4*a);
                    yf[4*a]=y.x; yf[4*a+1]=y.y; yf[4*a+2]=y.z; yf[4*a+3]=y.w; }
                bfrag8 o8;
                #pragma unroll
                for (int jj=0;jj<8;jj++)
                    o8[jj] = f2bf(v0*yf[jj*3] + v1*yf[jj*3+1] + v2*yf[jj*3+2]);
                *(bfrag8*)&sA[nd*1032 + kk0] = o8;
            }
        }
        __syncthreads();
        const short* bp = Wusst + (size_t)(w*16+col)*5120 + c*1024 + quad*8;
        #pragma unroll
        for (int s=0;s<32;s++){
            bfrag8 a = *(bfrag8*)&sA[col*1032 + s*32 + quad*8];
            bfrag8 b = *(const bfrag8*)(bp + s*32);
            acc = MFMA(a, b, acc);
        }
    }
    #pragma unroll
    for (int reg=0; reg<4; reg++){
        int nd = quad*4 + reg;
        int o = w*16 + col;
        ns_out[(size_t)(nb+nd)*64 + o] = ns16[nd*68 + o] + siluf(acc[reg]);
    }
}

// ---------------------------------------------------------------- u_v
__global__ __launch_bounds__(256) void k_uv(
        const float* __restrict__ ns, const float* __restrict__ nvv,
        const float* __restrict__ a_s, const float* __restrict__ a_v,
        const short* __restrict__ Wusvt, const short* __restrict__ Wuvst,
        const float* __restrict__ guw, const float* __restrict__ gub,
        float* __restrict__ nv_out)
{
    __shared__ __align__(16) short nsbf[16*72];
    __shared__ __align__(16) short asbf[16*72];
    __shared__ __align__(16) float nv16[16*100];
    __shared__ __align__(16) float av16[16*100];
    __shared__ float uvb[2][16][96];

    const int t = threadIdx.x;
    const int w = t>>6, lane = t&63, col = lane&15, quad = lane>>4;
    const int nb = blockIdx.x*16;

    for (int idx=t; idx<1024; idx+=256){ int nd = idx>>6, i = idx&63;
        nsbf[nd*72+i] = f2bf(ns[(size_t)(nb+nd)*64+i]);
        asbf[nd*72+i] = f2bf(a_s[(size_t)(nb+nd)*64+i]);
    }
    for (int idx=t; idx<1536; idx+=256){ int nd = idx/96, i = idx-nd*96;
        nv16[nd*100+i] = nvv[(size_t)(nb+nd)*96+i];
        av16[nd*100+i] = a_v[(size_t)(nb+nd)*96+i];
    }
    __syncthreads();

    const int h = w>>1, o0 = (w&1)*16;
    const short* src = h ? asbf : nsbf;
    bfrag8 a0 = *(bfrag8*)&src[col*72 + quad*8];
    bfrag8 a1 = *(bfrag8*)&src[col*72 + 32 + quad*8];
    const short* Bt = h ? Wuvst : Wusvt;
    const float* M  = h ? nv16 : av16;
    float uva[3][4] = {};
    for (int n=0;n<32;n++){
        f32x4 acc = {0.f,0.f,0.f,0.f};
        const short* bp = Bt + (size_t)((n<<5) + o0 + col)*64 + quad*8;
        bfrag8 b0 = *(const bfrag8*)(bp);
        bfrag8 b1 = *(const bfrag8*)(bp + 32);
        acc = MFMA(a0,b0,acc);
        acc = MFMA(a1,b1,acc);
        #pragma unroll
        for (int reg=0;reg<4;reg++){
            int nd = quad*4+reg;
            float m0 = M[nd*100 + n*3];
            float m1 = M[nd*100 + n*3+1];
            float m2 = M[nd*100 + n*3+2];
            uva[0][reg] += acc[reg]*m0;
            uva[1][reg] += acc[reg]*m1;
            uva[2][reg] += acc[reg]*m2;
        }
    }
    #pragma unroll
    for (int reg=0;reg<4;reg++){
        int nd = quad*4+reg;
        #pragma unroll
        for (int xx=0;xx<3;xx++)
            uvb[h][nd][(o0+col)*3+xx] = uva[xx][reg];
    }
    __syncthreads();
    {
        int nd = t>>4, j = t&15;
        float part = 0.f;
        #pragma unroll
        for (int kk=j; kk<96; kk+=16) part += uvb[0][nd][kk] + uvb[1][nd][kk];
        part += __shfl_xor(part,1); part += __shfl_xor(part,2);
        part += __shfl_xor(part,4); part += __shfl_xor(part,8);
        float mean = part*(1.0f/96.0f);
        #pragma unroll
        for (int q2=0;q2<6;q2++){
            int kk = j*6 + q2;
            float uv = uvb[0][nd][kk] + uvb[1][nd][kk];
            float g = sigm(mean*guw[kk] + gub[kk]);
            nv_out[(size_t)(nb+nd)*96 + kk] = nv16[nd*100+kk] + uv*g;
        }
    }
}

// ---------------------------------------------------------------- out = ns@Wout/8
__global__ __launch_bounds__(256) void k_out(const float* __restrict__ ns,
                                             const short* __restrict__ Woutt,
                                             float* __restrict__ outp)
{
    __shared__ __align__(16) short nsbf[16*72];
    const int t = threadIdx.x;
    const int w = t>>6, lane = t&63, col = lane&15, quad = lane>>4;
    const int nb = blockIdx.x*16;
    for (int idx=t; idx<1024; idx+=256){ int nd=idx>>6, i=idx&63;
        nsbf[nd*72+i] = f2bf(ns[(size_t)(nb+nd)*64+i]); }
    __syncthreads();
    bfrag8 a0 = *(bfrag8*)&nsbf[col*72 + quad*8];
    bfrag8 a1 = *(bfrag8*)&nsbf[col*72 + 32 + quad*8];
    #pragma unroll
    for (int nt=0;nt<4;nt++){
        int o = w*64 + nt*16 + col;
        const short* bp = Woutt + (size_t)o*64 + quad*8;
        bfrag8 b0 = *(const bfrag8*)bp;
        bfrag8 b1 = *(const bfrag8*)(bp+32);
        f32x4 acc = {0.f,0.f,0.f,0.f};
        acc = MFMA(a0,b0,acc);
        acc = MFMA(a1,b1,acc);
        #pragma unroll
        for (int reg=0;reg<4;reg++)
            outp[(size_t)(nb + quad*4+reg)*256 + o] = acc[reg];
    }
}

// ---------------------------------------------------------------- launch
extern "C" void kernel_launch(void* const* d_in, const int* in_sizes, int n_in,
                              void* d_out, int out_size, void* d_ws, size_t ws_size,
                              hipStream_t stream)
{
    const float* x     = (const float*)d_in[0];
    const float* eattr = (const float*)d_in[1];
    const float* Win   = (const float*)d_in[2];
    const float* Wout  = (const float*)d_in[3];
    const float* Wss   = (const float*)d_in[4];
    const float* Wvv0  = (const float*)d_in[5];
    const float* Wsv   = (const float*)d_in[6];
    const float* Wvs   = (const float*)d_in[7];
    const float* gmw   = (const float*)d_in[8];
    const float* gmb   = (const float*)d_in[9];
    const float* Wuss  = (const float*)d_in[10];
    const float* Wuvv  = (const float*)d_in[11];
    const float* Wusv  = (const float*)d_in[12];
    const float* Wuvs  = (const float*)d_in[13];
    const float* guw   = (const float*)d_in[14];
    const float* gub   = (const float*)d_in[15];
    const int*   eidx  = (const int*)d_in[16];
    float* outp = (float*)d_out;

    char* p = (char*)d_ws;
    float* ns_a = (float*)p; p += (size_t)N_NODES*64*4;
    float* ns_b = (float*)p; p += (size_t)N_NODES*64*4;
    float* nv_a = (float*)p; p += (size_t)N_NODES*96*4;
    float* nv_b = (float*)p; p += (size_t)N_NODES*96*4;
    float* a_s  = (float*)p; p += (size_t)N_NODES*64*4;   // a_s,a_v contiguous (one memset)
    float* a_v  = (float*)p; p += (size_t)N_NODES*96*4;
    int*   cnt    = (int*)p;   p += (size_t)N_NODES*4;
    int*   cursor = (int*)p;   p += (size_t)N_NODES*4;
    int*   col_s  = (int*)p;   p += (size_t)N_EDGES*4;
    int*   row_s  = (int*)p;   p += (size_t)N_EDGES*4;
    float4* ea_s  = (float4*)p; p += (size_t)N_EDGES*16;
    short* wp   = (short*)p;

    k_prep<<<3720, 256, 0, stream>>>(Wss,Wvv0,Wsv,Wvs,Wuss,Wuvv,Wusv,Wuvs,Wout,wp);
    hipMemsetAsync(nv_a, 0, (size_t)N_NODES*96*4, stream);
    hipMemsetAsync(cnt, 0, (size_t)N_NODES*4, stream);
    k_in<<<N_NODES/4, 256, 0, stream>>>(x, Win, ns_a);
    k_hist<<<N_EDGES/256, 256, 0, stream>>>(eidx, cnt);
    k_scan<<<1, 256, 0, stream>>>(cnt, cursor);
    k_scatter<<<N_EDGES/256, 256, 0, stream>>>(eidx, eattr, cursor, col_s, row_s, ea_s);

    for (int l=0;l<2;l++){
        const float* cns = l ? ns_b : ns_a;
        const float* cnv = l ? nv_b : nv_a;
        float* nns = l ? ns_a : ns_b;
        float* nnv = l ? nv_a : nv_b;
        hipMemsetAsync(a_s, 0, (size_t)N_NODES*(64+96)*4, stream);
        k_edge<<<N_EDGES/256, 256, 0, stream>>>(cns, cnv, col_s, row_s, ea_s,
                                         wp + (size_t)l*PREP_L,
                                         gmw + l*96, gmb + l*96, a_s, a_v);
        k_uv<<<N_NODES/16, 256, 0, stream>>>(cns, cnv, a_s, a_v,
                                             wp + (size_t)l*PREP_L + 336896,
                                             wp + (size_t)l*PREP_L + 402432,
                                             guw + l*96, gub + l*96, nnv);
        k_us<<<N_NODES/16, 256, 0, stream>>>(cns, cnv, a_s, a_v,
                                             wp + (size_t)l*PREP_L + 9216, nns);
    }
    k_out<<<N_NODES/16, 256, 0, stream>>>(ns_a, wp + (size_t)2*PREP_L, outp);
}